// Round 1
// baseline (3399.070 us; speedup 1.0000x reference)
//
#include <hip/hip_runtime.h>
#include <hip/hip_bf16.h>
#include <cstdint>
#include <cstddef>

typedef __hip_bfloat16 bf16;
typedef __attribute__((ext_vector_type(8))) short short8;
typedef __attribute__((ext_vector_type(4))) float floatx4;

// async global->LDS, 16B per lane. LDS dest = wave-uniform base + lane*16.
__device__ __forceinline__ void gload_lds16(const void* g, void* l) {
  __builtin_amdgcn_global_load_lds(
      (__attribute__((address_space(1))) void*)(uintptr_t)g,
      (__attribute__((address_space(3))) void*)l, 16, 0, 0);
}

__device__ __forceinline__ short f2bbits(float f) {
  bf16 h = __float2bfloat16(f);
  return __builtin_bit_cast(short, h);
}

// ---------------- x (fp32) -> xb (bf16), 8 elems/thread ----------------
__global__ __launch_bounds__(256) void convert_x(const float* __restrict__ x,
                                                 bf16* __restrict__ xb) {
  size_t i = ((size_t)blockIdx.x * 256 + threadIdx.x) * 8;
  float4 f0 = *(const float4*)(x + i);
  float4 f1 = *(const float4*)(x + i + 4);
  short8 r;
  r[0] = f2bbits(f0.x); r[1] = f2bbits(f0.y); r[2] = f2bbits(f0.z); r[3] = f2bbits(f0.w);
  r[4] = f2bbits(f1.x); r[5] = f2bbits(f1.y); r[6] = f2bbits(f1.z); r[7] = f2bbits(f1.w);
  *(short8*)(xb + i) = r;
}

// -------- W (1024 x cols, row-major fp32) -> dst[n][k] bf16 (transposed) --------
__global__ __launch_bounds__(256) void transpose_w(const float* __restrict__ src,
                                                   bf16* __restrict__ dst, int cols) {
  __shared__ float tile[32][33];
  int n0 = blockIdx.x * 32, k0 = blockIdx.y * 32;
  int tx = threadIdx.x & 31, ty = threadIdx.x >> 5;
#pragma unroll
  for (int i = 0; i < 32; i += 8) {
    int kk = k0 + ty + i, nn = n0 + tx;
    tile[ty + i][tx] = (nn < cols) ? src[(size_t)kk * cols + nn] : 0.0f;
  }
  __syncthreads();
#pragma unroll
  for (int i = 0; i < 32; i += 8) {
    int nn = n0 + ty + i, kk = k0 + tx;
    if (nn < cols) dst[(size_t)nn * 1024 + kk] = __float2bfloat16(tile[tx][ty + i]);
  }
}

// ---------------- 128x128-tile bf16 MFMA GEMM (m97 structure) ----------------
// C[M x N] = A[M x K] @ Bt[N x K]^T.  mode 0: projection epilogue (q,k,v,g,z)
// with N=3200 (512 q | 512 k | 1024 v | 1024 g | 16 z | 112 pad). mode 1: fp32 out.
__global__ __launch_bounds__(256, 2) void gemm128(
    const bf16* __restrict__ A, const bf16* __restrict__ Bt, int K, int mode,
    float* __restrict__ oq, float* __restrict__ okk, bf16* __restrict__ ov,
    bf16* __restrict__ ogg, float* __restrict__ oz, float* __restrict__ oo) {
  __shared__ __align__(16) bf16 sA[128 * 32];
  __shared__ __align__(16) bf16 sB[128 * 32];
  const int tid = threadIdx.x;
  const int wave = tid >> 6, lane = tid & 63;
  const int n0 = blockIdx.x * 128, m0 = blockIdx.y * 128;
  const int wm = (wave & 1) * 64, wn = (wave >> 1) * 64;
  const int srow = lane >> 2, scol = (lane & 3) * 8;
  floatx4 acc[4][4] = {};
  const int kIters = K >> 5;
  for (int kt = 0; kt < kIters; ++kt) {
    if (kt) __syncthreads();
    const int kO = (kt << 5) + scol;
#pragma unroll
    for (int c2 = 0; c2 < 2; ++c2) {
      const int chunk = wave * 2 + c2;
      gload_lds16(A + (size_t)(m0 + chunk * 16 + srow) * K + kO, &sA[chunk * 512]);
      gload_lds16(Bt + (size_t)(n0 + chunk * 16 + srow) * K + kO, &sB[chunk * 512]);
    }
    __syncthreads();  // drains vmcnt -> staged tiles visible
    const int l15 = lane & 15, q8 = (lane >> 4) * 8;
    short8 af[4], bfr[4];
#pragma unroll
    for (int i = 0; i < 4; ++i) af[i] = *(const short8*)&sA[(wm + i * 16 + l15) * 32 + q8];
#pragma unroll
    for (int j = 0; j < 4; ++j) bfr[j] = *(const short8*)&sB[(wn + j * 16 + l15) * 32 + q8];
#pragma unroll
    for (int i = 0; i < 4; ++i)
#pragma unroll
      for (int j = 0; j < 4; ++j)
        acc[i][j] = __builtin_amdgcn_mfma_f32_16x16x32_bf16(af[i], bfr[j], acc[i][j], 0, 0, 0);
  }
  // C/D layout (m89-verified): col = lane&15, row = (lane>>4)*4 + reg
  const int l15 = lane & 15, rq = (lane >> 4) * 4;
#pragma unroll
  for (int i = 0; i < 4; ++i) {
#pragma unroll
    for (int j = 0; j < 4; ++j) {
      const int n = n0 + wn + j * 16 + l15;
#pragma unroll
      for (int r = 0; r < 4; ++r) {
        const int m = m0 + wm + i * 16 + rq + r;
        const float val = acc[i][j][r];
        if (mode == 1) {
          oo[(size_t)m * 1024 + n] = val;
        } else {
          if (n < 512)       oq[(size_t)m * 512 + n] = val * 0.08838834764831845f;  // q * Dk^-0.5
          else if (n < 1024) okk[(size_t)m * 512 + (n - 512)] = val;
          else if (n < 2048) ov[(size_t)m * 1024 + (n - 1024)] = __float2bfloat16(val);
          else if (n < 3072) ogg[(size_t)m * 1024 + (n - 2048)] = __float2bfloat16(val);
          else if (n < 3088) oz[(size_t)m * 16 + (n - 3072)] = val;
          // n >= 3088: padding, drop
        }
      }
    }
  }
}

// ------------- aexp = exp(log_sigmoid(z @ w2 + b2) / 16), per row -------------
__global__ __launch_bounds__(256) void gate_decay(const float* __restrict__ z,
                                                  const float* __restrict__ w2,
                                                  const float* __restrict__ b2,
                                                  float* __restrict__ aexp) {
  __shared__ float sz[16];
  const int m = blockIdx.x, tid = threadIdx.x;
  if (tid < 16) sz[tid] = z[(size_t)m * 16 + tid];
  __syncthreads();
#pragma unroll
  for (int u = 0; u < 2; ++u) {
    const int n = tid + u * 256;
    float t = b2[n];
#pragma unroll
    for (int j = 0; j < 16; ++j) t = fmaf(sz[j], w2[j * 512 + n], t);
    const float ls = fminf(t, 0.0f) - log1pf(expf(-fabsf(t)));  // log_sigmoid(t)
    aexp[(size_t)m * 512 + n] = expf(0.0625f * ls);
  }
}

// ---------------- sequential GLA recurrence ----------------
// grid (16 colgroups, 4 heads, 8 batch), block 256 = 16 cols x 16 subs.
// thread (sub, col): owns S[rows sub*8..sub*8+7][col]; o reduced over 16 subs via shfl.
__global__ __launch_bounds__(256, 2) void recur(
    const float* __restrict__ qg, const float* __restrict__ kg,
    const float* __restrict__ ag, const bf16* __restrict__ vg,
    bf16* __restrict__ og) {
  const int cg = blockIdx.x, h = blockIdx.y, b = blockIdx.z;
  const int tid = threadIdx.x;
  const int sub = tid & 15, colslot = tid >> 4;
  const int r0 = sub * 8;
  const int c = cg * 16 + colslot;
  const size_t qkBase = ((size_t)b * 4096) * 512 + h * 128 + r0;
  const size_t vBase = ((size_t)b * 4096) * 1024 + h * 256 + c;
  float S0 = 0, S1 = 0, S2 = 0, S3 = 0, S4 = 0, S5 = 0, S6 = 0, S7 = 0;
  int oQ = 0, oV = 0;
  for (int t = 0; t < 4096; ++t) {
    const float4 a0 = *(const float4*)(ag + qkBase + oQ);
    const float4 a1 = *(const float4*)(ag + qkBase + oQ + 4);
    const float4 k0 = *(const float4*)(kg + qkBase + oQ);
    const float4 k1 = *(const float4*)(kg + qkBase + oQ + 4);
    const float4 q0 = *(const float4*)(qg + qkBase + oQ);
    const float4 q1 = *(const float4*)(qg + qkBase + oQ + 4);
    const float vv = __bfloat162float(vg[vBase + oV]);
    float p;
    S0 = fmaf(a0.x, S0, k0.x * vv); p = q0.x * S0;
    S1 = fmaf(a0.y, S1, k0.y * vv); p = fmaf(q0.y, S1, p);
    S2 = fmaf(a0.z, S2, k0.z * vv); p = fmaf(q0.z, S2, p);
    S3 = fmaf(a0.w, S3, k0.w * vv); p = fmaf(q0.w, S3, p);
    S4 = fmaf(a1.x, S4, k1.x * vv); p = fmaf(q1.x, S4, p);
    S5 = fmaf(a1.y, S5, k1.y * vv); p = fmaf(q1.y, S5, p);
    S6 = fmaf(a1.z, S6, k1.z * vv); p = fmaf(q1.z, S6, p);
    S7 = fmaf(a1.w, S7, k1.w * vv); p = fmaf(q1.w, S7, p);
    p += __shfl_xor(p, 1);
    p += __shfl_xor(p, 2);
    p += __shfl_xor(p, 4);
    p += __shfl_xor(p, 8);
    if (sub == 0) og[vBase + oV] = __float2bfloat16(p);
    oQ += 512; oV += 1024;
  }
}

// ---------------- per-head RMSNorm * g_norm_w, then * swish(g) ----------------
__global__ __launch_bounds__(1024) void norm_gate(
    const bf16* __restrict__ o, const bf16* __restrict__ g,
    const float* __restrict__ gnw, bf16* __restrict__ og) {
  __shared__ float sp[16];
  const int tid = threadIdx.x;
  const size_t idx = (size_t)blockIdx.x * 1024 + tid;
  const float f = __bfloat162float(o[idx]);
  float ss = f * f;
#pragma unroll
  for (int mm = 1; mm <= 32; mm <<= 1) ss += __shfl_xor(ss, mm);
  if ((tid & 63) == 0) sp[tid >> 6] = ss;
  __syncthreads();
  const int h4 = (tid >> 8) * 4;  // 4 waves per head
  const float ms = (sp[h4] + sp[h4 + 1] + sp[h4 + 2] + sp[h4 + 3]) * (1.0f / 256.0f);
  const float scale = rsqrtf(ms + 1e-5f) * gnw[tid & 255];
  const float gv = __bfloat162float(g[idx]);
  const float sw = gv * (1.0f / (1.0f + expf(-gv)));
  og[idx] = __float2bfloat16(f * scale * sw);
}

extern "C" void kernel_launch(void* const* d_in, const int* in_sizes, int n_in,
                              void* d_out, int out_size, void* d_ws, size_t ws_size,
                              hipStream_t stream) {
  const float* x   = (const float*)d_in[0];
  const float* Wq  = (const float*)d_in[1];
  const float* Wk  = (const float*)d_in[2];
  const float* Wv  = (const float*)d_in[3];
  const float* gw1 = (const float*)d_in[4];
  const float* gw2 = (const float*)d_in[5];
  const float* gb2 = (const float*)d_in[6];
  const float* Wg  = (const float*)d_in[7];
  const float* gnw = (const float*)d_in[8];
  const float* Wo  = (const float*)d_in[9];
  float* out = (float*)d_out;

  // workspace carve (total 413,401,088 B). o_raw aliases xb (dead after proj GEMM);
  // o_gated aliases aexp (dead after recurrence).
  uint8_t* w = (uint8_t*)d_ws;
  bf16*  xb    = (bf16*)(w);
  bf16*  wallT = (bf16*)(w + 67108864);   // 3200 x 1024 bf16
  bf16*  woT   = (bf16*)(w + 73662464);   // 1024 x 1024 bf16
  float* qb    = (float*)(w + 75759616);  // 32768 x 512 fp32 (pre-scaled)
  float* kb    = (float*)(w + 142868480); // 32768 x 512 fp32
  float* ab    = (float*)(w + 209977344); // 32768 x 512 fp32  exp(gk)
  bf16*  vb    = (bf16*)(w + 277086208);  // 32768 x 1024 bf16
  bf16*  gb    = (bf16*)(w + 344195072);  // 32768 x 1024 bf16
  float* zb    = (float*)(w + 411303936); // 32768 x 16 fp32
  bf16*  oraw  = xb;
  bf16*  ogat  = (bf16*)ab;

  convert_x<<<dim3(16384), 256, 0, stream>>>(x, xb);
  transpose_w<<<dim3(16, 32), 256, 0, stream>>>(Wq, wallT, 512);
  transpose_w<<<dim3(16, 32), 256, 0, stream>>>(Wk, wallT + (size_t)512 * 1024, 512);
  transpose_w<<<dim3(32, 32), 256, 0, stream>>>(Wv, wallT + (size_t)1024 * 1024, 1024);
  transpose_w<<<dim3(32, 32), 256, 0, stream>>>(Wg, wallT + (size_t)2048 * 1024, 1024);
  transpose_w<<<dim3(1, 32), 256, 0, stream>>>(gw1, wallT + (size_t)3072 * 1024, 16);
  transpose_w<<<dim3(32, 32), 256, 0, stream>>>(Wo, woT, 1024);
  // fused projection GEMM: n-fastest grid keeps the 6.5MB weight panel L2-resident
  gemm128<<<dim3(25, 256), 256, 0, stream>>>(xb, wallT, 1024, 0, qb, kb, vb, gb, zb, nullptr);
  gate_decay<<<dim3(32768), 256, 0, stream>>>(zb, gw2, gb2, ab);
  recur<<<dim3(16, 4, 8), 256, 0, stream>>>(qb, kb, ab, vb, oraw);
  norm_gate<<<dim3(32768), 1024, 0, stream>>>(oraw, gb, gnw, ogat);
  gemm128<<<dim3(8, 256), 256, 0, stream>>>(ogat, woT, 1024, 1, nullptr, nullptr, nullptr, nullptr, nullptr, out);
}

// Round 2
// 2931.777 us; speedup vs baseline: 1.1594x; 1.1594x over previous
//
#include <hip/hip_runtime.h>
#include <hip/hip_bf16.h>
#include <cstdint>
#include <cstddef>

typedef __hip_bfloat16 bf16;
typedef __attribute__((ext_vector_type(8))) short short8;
typedef __attribute__((ext_vector_type(4))) float floatx4;

// async global->LDS, 16B per lane. LDS dest = wave-uniform base + lane*16.
__device__ __forceinline__ void gload_lds16(const void* g, void* l) {
  __builtin_amdgcn_global_load_lds(
      (__attribute__((address_space(1))) void*)(uintptr_t)g,
      (__attribute__((address_space(3))) void*)l, 16, 0, 0);
}

__device__ __forceinline__ short f2bbits(float f) {
  bf16 h = __float2bfloat16(f);
  return __builtin_bit_cast(short, h);
}

// ---------------- x (fp32) -> xb (bf16), 8 elems/thread ----------------
__global__ __launch_bounds__(256) void convert_x(const float* __restrict__ x,
                                                 bf16* __restrict__ xb) {
  size_t i = ((size_t)blockIdx.x * 256 + threadIdx.x) * 8;
  float4 f0 = *(const float4*)(x + i);
  float4 f1 = *(const float4*)(x + i + 4);
  short8 r;
  r[0] = f2bbits(f0.x); r[1] = f2bbits(f0.y); r[2] = f2bbits(f0.z); r[3] = f2bbits(f0.w);
  r[4] = f2bbits(f1.x); r[5] = f2bbits(f1.y); r[6] = f2bbits(f1.z); r[7] = f2bbits(f1.w);
  *(short8*)(xb + i) = r;
}

// -------- W (1024 x cols, row-major fp32) -> dst[n][k] bf16 (transposed) --------
__global__ __launch_bounds__(256) void transpose_w(const float* __restrict__ src,
                                                   bf16* __restrict__ dst, int cols) {
  __shared__ float tile[32][33];
  int n0 = blockIdx.x * 32, k0 = blockIdx.y * 32;
  int tx = threadIdx.x & 31, ty = threadIdx.x >> 5;
#pragma unroll
  for (int i = 0; i < 32; i += 8) {
    int kk = k0 + ty + i, nn = n0 + tx;
    tile[ty + i][tx] = (nn < cols) ? src[(size_t)kk * cols + nn] : 0.0f;
  }
  __syncthreads();
#pragma unroll
  for (int i = 0; i < 32; i += 8) {
    int nn = n0 + ty + i, kk = k0 + tx;
    if (nn < cols) dst[(size_t)nn * 1024 + kk] = __float2bfloat16(tile[tx][ty + i]);
  }
}

// ---------------- 128x128-tile bf16 MFMA GEMM (m97 structure) ----------------
// C[M x N] = A[M x K] @ Bt[N x K]^T.  mode 0: projection epilogue (q,k,v,g,z)
// with N=3200 (512 q | 512 k | 1024 v | 1024 g | 16 z | 112 pad). mode 1: fp32 out.
__global__ __launch_bounds__(256, 2) void gemm128(
    const bf16* __restrict__ A, const bf16* __restrict__ Bt, int K, int mode,
    float* __restrict__ oq, float* __restrict__ okk, bf16* __restrict__ ov,
    bf16* __restrict__ ogg, float* __restrict__ oz, float* __restrict__ oo) {
  __shared__ __align__(16) bf16 sA[128 * 32];
  __shared__ __align__(16) bf16 sB[128 * 32];
  const int tid = threadIdx.x;
  const int wave = tid >> 6, lane = tid & 63;
  const int n0 = blockIdx.x * 128, m0 = blockIdx.y * 128;
  const int wm = (wave & 1) * 64, wn = (wave >> 1) * 64;
  const int srow = lane >> 2, scol = (lane & 3) * 8;
  floatx4 acc[4][4] = {};
  const int kIters = K >> 5;
  for (int kt = 0; kt < kIters; ++kt) {
    if (kt) __syncthreads();
    const int kO = (kt << 5) + scol;
#pragma unroll
    for (int c2 = 0; c2 < 2; ++c2) {
      const int chunk = wave * 2 + c2;
      gload_lds16(A + (size_t)(m0 + chunk * 16 + srow) * K + kO, &sA[chunk * 512]);
      gload_lds16(Bt + (size_t)(n0 + chunk * 16 + srow) * K + kO, &sB[chunk * 512]);
    }
    __syncthreads();  // drains vmcnt -> staged tiles visible
    const int l15 = lane & 15, q8 = (lane >> 4) * 8;
    short8 af[4], bfr[4];
#pragma unroll
    for (int i = 0; i < 4; ++i) af[i] = *(const short8*)&sA[(wm + i * 16 + l15) * 32 + q8];
#pragma unroll
    for (int j = 0; j < 4; ++j) bfr[j] = *(const short8*)&sB[(wn + j * 16 + l15) * 32 + q8];
#pragma unroll
    for (int i = 0; i < 4; ++i)
#pragma unroll
      for (int j = 0; j < 4; ++j)
        acc[i][j] = __builtin_amdgcn_mfma_f32_16x16x32_bf16(af[i], bfr[j], acc[i][j], 0, 0, 0);
  }
  // C/D layout (m89-verified): col = lane&15, row = (lane>>4)*4 + reg
  const int l15 = lane & 15, rq = (lane >> 4) * 4;
#pragma unroll
  for (int i = 0; i < 4; ++i) {
#pragma unroll
    for (int j = 0; j < 4; ++j) {
      const int n = n0 + wn + j * 16 + l15;
#pragma unroll
      for (int r = 0; r < 4; ++r) {
        const int m = m0 + wm + i * 16 + rq + r;
        const float val = acc[i][j][r];
        if (mode == 1) {
          oo[(size_t)m * 1024 + n] = val;
        } else {
          if (n < 512)       oq[(size_t)m * 512 + n] = val * 0.08838834764831845f;  // q * Dk^-0.5
          else if (n < 1024) okk[(size_t)m * 512 + (n - 512)] = val;
          else if (n < 2048) ov[(size_t)m * 1024 + (n - 1024)] = __float2bfloat16(val);
          else if (n < 3072) ogg[(size_t)m * 1024 + (n - 2048)] = __float2bfloat16(val);
          else if (n < 3088) oz[(size_t)m * 16 + (n - 3072)] = val;
          // n >= 3088: padding, drop
        }
      }
    }
  }
}

// ------------- aexp = exp(log_sigmoid(z @ w2 + b2) / 16), per row -------------
__global__ __launch_bounds__(256) void gate_decay(const float* __restrict__ z,
                                                  const float* __restrict__ w2,
                                                  const float* __restrict__ b2,
                                                  float* __restrict__ aexp) {
  __shared__ float sz[16];
  const int m = blockIdx.x, tid = threadIdx.x;
  if (tid < 16) sz[tid] = z[(size_t)m * 16 + tid];
  __syncthreads();
#pragma unroll
  for (int u = 0; u < 2; ++u) {
    const int n = tid + u * 256;
    float t = b2[n];
#pragma unroll
    for (int j = 0; j < 16; ++j) t = fmaf(sz[j], w2[j * 512 + n], t);
    const float ls = fminf(t, 0.0f) - log1pf(expf(-fabsf(t)));  // log_sigmoid(t)
    aexp[(size_t)m * 512 + n] = expf(0.0625f * ls);
  }
}

// ---------------- sequential GLA recurrence (R2: 4-deep prefetch, 1024 blocks) ----
// grid (32 colgroups, 4 heads, 8 batch) = 1024 blocks -> 4 blocks/CU, 16 waves/CU.
// block 256 = 8 cols x 32 subs; thread (sub,col) owns S[rows sub*4..+3][col].
// o reduced over 32 subs via 5x shfl_xor. 4-deep register prefetch hides L2 latency.
// Prefetch over-reads up to 4 rows past t=4095: stays inside ws (qb->kb->ab->vb->gb).
__global__ __launch_bounds__(256, 4) void recur(
    const float* __restrict__ qg, const float* __restrict__ kg,
    const float* __restrict__ ag, const bf16* __restrict__ vg,
    bf16* __restrict__ og) {
  const int cg = blockIdx.x, h = blockIdx.y, b = blockIdx.z;
  const int tid = threadIdx.x;
  const int sub = tid & 31, colslot = tid >> 5;
  const int r0 = sub * 4;
  const int c = cg * 8 + colslot;
  const float* qp = qg + ((size_t)b * 4096) * 512 + h * 128 + r0;
  const float* kp = kg + ((size_t)b * 4096) * 512 + h * 128 + r0;
  const float* ap = ag + ((size_t)b * 4096) * 512 + h * 128 + r0;
  const bf16*  vp = vg + ((size_t)b * 4096) * 1024 + h * 256 + c;
  bf16*        op = og + ((size_t)b * 4096) * 1024 + h * 256 + c;

  float4 Q[4], K[4], A[4];
  float  V[4];
#pragma unroll
  for (int s = 0; s < 4; ++s) {
    Q[s] = *(const float4*)(qp + (size_t)s * 512);
    K[s] = *(const float4*)(kp + (size_t)s * 512);
    A[s] = *(const float4*)(ap + (size_t)s * 512);
    V[s] = __bfloat162float(vp[(size_t)s * 1024]);
  }
  float S0 = 0, S1 = 0, S2 = 0, S3 = 0;
  for (int t = 0; t < 4096; t += 4) {
#pragma unroll
    for (int s = 0; s < 4; ++s) {
      const float4 q = Q[s], k = K[s], a = A[s];
      const float vv = V[s];
      // prefetch t+4+s (over-read past end is inside ws, values unused)
      const size_t tn = (size_t)(t + 4 + s);
      Q[s] = *(const float4*)(qp + tn * 512);
      K[s] = *(const float4*)(kp + tn * 512);
      A[s] = *(const float4*)(ap + tn * 512);
      V[s] = __bfloat162float(vp[tn * 1024]);
      float p;
      S0 = fmaf(a.x, S0, k.x * vv); p = q.x * S0;
      S1 = fmaf(a.y, S1, k.y * vv); p = fmaf(q.y, S1, p);
      S2 = fmaf(a.z, S2, k.z * vv); p = fmaf(q.z, S2, p);
      S3 = fmaf(a.w, S3, k.w * vv); p = fmaf(q.w, S3, p);
      p += __shfl_xor(p, 1);
      p += __shfl_xor(p, 2);
      p += __shfl_xor(p, 4);
      p += __shfl_xor(p, 8);
      p += __shfl_xor(p, 16);
      if (sub == 0) op[(size_t)(t + s) * 1024] = __float2bfloat16(p);
    }
  }
}

// ---------------- per-head RMSNorm * g_norm_w, then * swish(g) ----------------
__global__ __launch_bounds__(1024) void norm_gate(
    const bf16* __restrict__ o, const bf16* __restrict__ g,
    const float* __restrict__ gnw, bf16* __restrict__ og) {
  __shared__ float sp[16];
  const int tid = threadIdx.x;
  const size_t idx = (size_t)blockIdx.x * 1024 + tid;
  const float f = __bfloat162float(o[idx]);
  float ss = f * f;
#pragma unroll
  for (int mm = 1; mm <= 32; mm <<= 1) ss += __shfl_xor(ss, mm);
  if ((tid & 63) == 0) sp[tid >> 6] = ss;
  __syncthreads();
  const int h4 = (tid >> 8) * 4;  // 4 waves per head
  const float ms = (sp[h4] + sp[h4 + 1] + sp[h4 + 2] + sp[h4 + 3]) * (1.0f / 256.0f);
  const float scale = rsqrtf(ms + 1e-5f) * gnw[tid & 255];
  const float gv = __bfloat162float(g[idx]);
  const float sw = gv * (1.0f / (1.0f + expf(-gv)));
  og[idx] = __float2bfloat16(f * scale * sw);
}

extern "C" void kernel_launch(void* const* d_in, const int* in_sizes, int n_in,
                              void* d_out, int out_size, void* d_ws, size_t ws_size,
                              hipStream_t stream) {
  const float* x   = (const float*)d_in[0];
  const float* Wq  = (const float*)d_in[1];
  const float* Wk  = (const float*)d_in[2];
  const float* Wv  = (const float*)d_in[3];
  const float* gw1 = (const float*)d_in[4];
  const float* gw2 = (const float*)d_in[5];
  const float* gb2 = (const float*)d_in[6];
  const float* Wg  = (const float*)d_in[7];
  const float* gnw = (const float*)d_in[8];
  const float* Wo  = (const float*)d_in[9];
  float* out = (float*)d_out;

  // workspace carve (total 413,401,088 B). o_raw aliases xb (dead after proj GEMM);
  // o_gated aliases aexp (dead after recurrence).
  uint8_t* w = (uint8_t*)d_ws;
  bf16*  xb    = (bf16*)(w);
  bf16*  wallT = (bf16*)(w + 67108864);   // 3200 x 1024 bf16
  bf16*  woT   = (bf16*)(w + 73662464);   // 1024 x 1024 bf16
  float* qb    = (float*)(w + 75759616);  // 32768 x 512 fp32 (pre-scaled)
  float* kb    = (float*)(w + 142868480); // 32768 x 512 fp32
  float* ab    = (float*)(w + 209977344); // 32768 x 512 fp32  exp(gk)
  bf16*  vb    = (bf16*)(w + 277086208);  // 32768 x 1024 bf16
  bf16*  gb    = (bf16*)(w + 344195072);  // 32768 x 1024 bf16
  float* zb    = (float*)(w + 411303936); // 32768 x 16 fp32
  bf16*  oraw  = xb;
  bf16*  ogat  = (bf16*)ab;

  convert_x<<<dim3(16384), 256, 0, stream>>>(x, xb);
  transpose_w<<<dim3(16, 32), 256, 0, stream>>>(Wq, wallT, 512);
  transpose_w<<<dim3(16, 32), 256, 0, stream>>>(Wk, wallT + (size_t)512 * 1024, 512);
  transpose_w<<<dim3(32, 32), 256, 0, stream>>>(Wv, wallT + (size_t)1024 * 1024, 1024);
  transpose_w<<<dim3(32, 32), 256, 0, stream>>>(Wg, wallT + (size_t)2048 * 1024, 1024);
  transpose_w<<<dim3(1, 32), 256, 0, stream>>>(gw1, wallT + (size_t)3072 * 1024, 16);
  transpose_w<<<dim3(32, 32), 256, 0, stream>>>(Wo, woT, 1024);
  // fused projection GEMM: n-fastest grid keeps the 6.5MB weight panel L2-resident
  gemm128<<<dim3(25, 256), 256, 0, stream>>>(xb, wallT, 1024, 0, qb, kb, vb, gb, zb, nullptr);
  gate_decay<<<dim3(32768), 256, 0, stream>>>(zb, gw2, gb2, ab);
  recur<<<dim3(32, 4, 8), 256, 0, stream>>>(qb, kb, ab, vb, oraw);
  norm_gate<<<dim3(32768), 1024, 0, stream>>>(oraw, gb, gnw, ogat);
  gemm128<<<dim3(8, 256), 256, 0, stream>>>(ogat, woT, 1024, 1, nullptr, nullptr, nullptr, nullptr, nullptr, out);
}